// Round 6
// baseline (205.015 us; speedup 1.0000x reference)
//
#include <hip/hip_runtime.h>

#define NCLS 80
#define BATCH 32
#define N0 (BATCH * 80 * 80)   // 204800
#define N1 (BATCH * 40 * 40)   // 51200
#define N2 (BATCH * 20 * 20)   // 12800
#define NCELL (N0 + N1 + N2)   // 268800
#define NFLT (NCELL * (NCLS + 5))     // 22,848,000 floats total
#define NF4  (NFLT / 4)               // 5,712,000 float4s
#define L0F4 ((N0 * (NCLS + 5)) / 4)  // 4,352,000 (level-0 float4s)
#define L01F4 (((N0 + N1) * (NCLS + 5)) / 4)  // 5,440,000
#define TPB 256
#define WPB (TPB / 64)                // waves per block
#define STREAM_BLOCKS 2048
#define STRIDE4 (STREAM_BLOCKS * TPB) // 524288 float4s per sweep
#define NBMAX 2400                    // STREAM_BLOCKS + up to 352 target blocks

// Per-block partials: [0..2]=lbox_s, [3..5]=lcls_s, [6..8]=cnt, [9..11]=lobj_s
// Written unconditionally by every block every call -> no zero-init needed.
__device__ float g_part[NBMAX * 12];
// Arrival counter for the last-block-done fused reduction. Zero at module
// load (.bss); the finishing block resets it to 0 -> self-sustaining across
// graph replays, no memset required, no co-residency assumption.
__device__ int g_done;

__device__ __forceinline__ float sigmoid_f(float x) {
    return 1.0f / (1.0f + expf(-x));
}

__device__ __forceinline__ float softplus_f(float x) {
    // stable: max(x,0) + log1p(exp(-|x|))
    return fmaxf(x, 0.0f) + log1pf(expf(-fabsf(x)));
}

__device__ __forceinline__ float ciou_f(float px, float py, float pw, float ph,
                                        float tx, float ty, float tw, float th) {
    const float eps = 1e-7f;
    float b1x1 = px - pw * 0.5f, b1x2 = px + pw * 0.5f;
    float b1y1 = py - ph * 0.5f, b1y2 = py + ph * 0.5f;
    float b2x1 = tx - tw * 0.5f, b2x2 = tx + tw * 0.5f;
    float b2y1 = ty - th * 0.5f, b2y2 = ty + th * 0.5f;
    float iw = fmaxf(fminf(b1x2, b2x2) - fmaxf(b1x1, b2x1), 0.0f);
    float ih = fmaxf(fminf(b1y2, b2y2) - fmaxf(b1y1, b2y1), 0.0f);
    float inter = iw * ih;
    float uni = pw * ph + tw * th - inter + eps;
    float iou = inter / uni;
    float cw = fmaxf(b1x2, b2x2) - fminf(b1x1, b2x1);
    float ch = fmaxf(b1y2, b2y2) - fminf(b1y1, b2y1);
    float c2 = cw * cw + ch * ch + eps;
    float dx = b2x1 + b2x2 - b1x1 - b1x2;
    float dy = b2y1 + b2y2 - b1y1 - b1y2;
    float rho2 = (dx * dx + dy * dy) * 0.25f;
    float dat = atanf(tw / th) - atanf(pw / ph);
    const float k = 0.40528473456935108577551785f; // 4/pi^2
    float v = k * dat * dat;
    float alpha = v / (v - iou + (1.0f + eps));
    return iou - (rho2 / c2 + v * alpha);
}

// One stream-sweep body: float4 at flat index i4; residue r = (4*i4) % 85.
// Element e contributes iff e % 85 == 4 (objectness channel); within this
// float4 that's component j = 4 - r when 1 <= r <= 4. Branchless masked
// accumulate keeps the 16B load unconditionally live (round-3 lesson: a
// conditional use lets LLVM sink the load into a rare branch -> gather).
__device__ __forceinline__ void stream_body(
        const float4* __restrict__ f0, const float4* __restrict__ f1,
        const float4* __restrict__ f2, int i4, unsigned int r,
        float& acc0, float& acc1, float& acc2) {
    const float4* src;
    int off, lvl;
    if (i4 < L0F4)       { src = f0; off = i4;         lvl = 0; }
    else if (i4 < L01F4) { src = f1; off = i4 - L0F4;  lvl = 1; }
    else                 { src = f2; off = i4 - L01F4; lvl = 2; }
    float4 v = src[off];
    unsigned int j = 4u - r;  // valid when 1<=r<=4; masked out otherwise
    float x = (j == 0u) ? v.x : (j == 1u) ? v.y : (j == 2u) ? v.z : v.w;
    float maskf = (r >= 1u && r <= 4u) ? 1.0f : 0.0f;
    float sp = maskf * softplus_f(x);
    acc0 += (lvl == 0) ? sp : 0.0f;
    acc1 += (lvl == 1) ? sp : 0.0f;
    acc2 += (lvl == 2) ? sp : 0.0f;
}

__global__ __launch_bounds__(TPB) void main_kernel(
        const float* __restrict__ p0,
        const float* __restrict__ p1,
        const float* __restrict__ p2,
        const float* __restrict__ tg, int nt, int tgtBlocks, int nblk,
        float* __restrict__ out) {
    __shared__ float sh[12];
    __shared__ int lastFlag;
    int tid = threadIdx.x;
    if (tid < 12) sh[tid] = 0.0f;
    __syncthreads();

    if ((int)blockIdx.x >= tgtBlocks) {
        // ========== coalesced stream path: lobj softplus term ==========
        const float4* f0 = (const float4*)p0;
        const float4* f1 = (const float4*)p1;
        const float4* f2 = (const float4*)p2;
        int i4 = (blockIdx.x - tgtBlocks) * TPB + tid;
        // residue of 4*i4 mod 85; per-sweep increment: (4*STRIDE4) % 85 == 32
        unsigned int r = ((unsigned int)i4 * 4u) % 85u;
        float acc0 = 0.0f, acc1 = 0.0f, acc2 = 0.0f;
        // 8x manual unroll: independent bodies -> 8 loads in flight per wave
        while (i4 + 7 * STRIDE4 < NF4) {
            unsigned int rr[8];
            rr[0] = r;
            #pragma unroll
            for (int u = 1; u < 8; u++) {
                rr[u] = rr[u - 1] + 32u;
                if (rr[u] >= 85u) rr[u] -= 85u;
            }
            #pragma unroll
            for (int u = 0; u < 8; u++)
                stream_body(f0, f1, f2, i4 + u * STRIDE4, rr[u],
                            acc0, acc1, acc2);
            r = rr[7] + 32u; if (r >= 85u) r -= 85u;
            i4 += 8 * STRIDE4;
        }
        while (i4 < NF4) {
            stream_body(f0, f1, f2, i4, r, acc0, acc1, acc2);
            r += 32u; if (r >= 85u) r -= 85u;
            i4 += STRIDE4;
        }
        // wave reduce (lanes reconverged), then 3 LDS atomics per wave
        #pragma unroll
        for (int off = 32; off > 0; off >>= 1) {
            acc0 += __shfl_down(acc0, off, 64);
            acc1 += __shfl_down(acc1, off, 64);
            acc2 += __shfl_down(acc2, off, 64);
        }
        if ((tid & 63) == 0) {
            atomicAdd(&sh[9], acc0);
            atomicAdd(&sh[10], acc1);
            atomicAdd(&sh[11], acc2);
        }
    } else {
        // ========== target path: ONE WAVE per (level, target) ==========
        // 85-float pred row read as two coalesced wave loads (pr[lane],
        // pr[64+lane] for lane<21); class softplus lane-parallel; box/obj
        // channels broadcast via shfl; CIoU computed uniformly on all lanes.
        int lane = tid & 63;
        int wtask = blockIdx.x * WPB + (tid >> 6);
        if (wtask < 3 * nt) {
            int lvl = wtask / nt;
            int t = wtask - lvl * nt;

            int W = (lvl == 0) ? 80 : ((lvl == 1) ? 40 : 20);
            float s = (lvl == 0) ? 8.0f : ((lvl == 1) ? 16.0f : 32.0f);
            const float* p = (lvl == 0) ? p0 : ((lvl == 1) ? p1 : p2);

            const float* row = tg + t * 6;
            float bf = row[0], cf = row[1];
            float x = row[2], y = row[3], w = row[4], h = row[5];

            float Wf = (float)W;
            float gw = w * Wf, gh = h * Wf;   // gain (H == W per level)
            float rw = gw / s, rh = gh / s;
            float m = fmaxf(fmaxf(rw, 1.0f / rw), fmaxf(rh, 1.0f / rh));
            if (m < 4.0f) {                   // keep filter (wave-uniform)
                float gx = x * Wf, gy = y * Wf;
                int b = (int)bf;
                int c = (int)cf;

                // offset candidates; jj/ll and kk/mm mutually exclusive -> ne<=3
                float ox[3], oy[3];
                int ne = 0;
                ox[ne] = 0.0f; oy[ne] = 0.0f; ne++;
                bool jj = (fmodf(gx, 1.0f) < 0.5f) && (gx > 1.0f);
                bool kk = (fmodf(gy, 1.0f) < 0.5f) && (gy > 1.0f);
                float gxi = Wf - gx, gyi = Wf - gy;
                bool ll = (fmodf(gxi, 1.0f) < 0.5f) && (gxi > 1.0f);
                bool mm = (fmodf(gyi, 1.0f) < 0.5f) && (gyi > 1.0f);
                if (jj) { ox[ne] = 0.5f;  oy[ne] = 0.0f;  ne++; }
                if (ll) { ox[ne] = -0.5f; oy[ne] = 0.0f;  ne++; }
                if (kk) { ox[ne] = 0.0f;  oy[ne] = 0.5f;  ne++; }
                if (mm) { ox[ne] = 0.0f;  oy[ne] = -0.5f; ne++; }

                float cls_lane = 0.0f;        // distributed across lanes
                float lbox_u = 0.0f, lobj_u = 0.0f;  // wave-uniform
                int hot = 5 + c;              // one-hot class channel
                for (int e = 0; e < ne; e++) {
                    int gi = (int)(gx - ox[e]);  // operands > 0: trunc == floor
                    int gj = (int)(gy - oy[e]);
                    gi = min(max(gi, 0), W - 1);
                    gj = min(max(gj, 0), W - 1);
                    int cell = (b * W + gj) * W + gi;  // a == 0
                    const float* pr = p + (size_t)cell * (NCLS + 5);

                    float v1 = pr[lane];                              // 0..63
                    float v2 = (lane < 21) ? pr[64 + lane] : 0.0f;    // 64..84

                    float c0 = __shfl(v1, 0, 64);
                    float c1 = __shfl(v1, 1, 64);
                    float c2 = __shfl(v1, 2, 64);
                    float c3 = __shfl(v1, 3, 64);
                    float c4 = __shfl(v1, 4, 64);

                    float px = sigmoid_f(c0) * 2.0f - 0.5f;
                    float py = sigmoid_f(c1) * 2.0f - 0.5f;
                    float sw = sigmoid_f(c2) * 2.0f;
                    float shh = sigmoid_f(c3) * 2.0f;
                    float pw = sw * sw * s;
                    float ph = shh * shh * s;

                    float tbx = gx - (float)gi;
                    float tby = gy - (float)gj;

                    float iou = ciou_f(px, py, pw, ph, tbx, tby, gw, gh);
                    lbox_u += 1.0f - iou;
                    lobj_u += c4 * fmaxf(iou, 0.0f);  // x4 * tobj scatter term

                    // class BCE: sum softplus over channels 5..84, minus the
                    // logit at the one-hot channel
                    float s1 = (lane >= 5) ? softplus_f(v1) : 0.0f;
                    float s2 = (lane < 21) ? softplus_f(v2) : 0.0f;
                    cls_lane += s1 + s2;
                    if (hot < 64) { if (lane == hot)      cls_lane -= v1; }
                    else          { if (lane == hot - 64) cls_lane -= v2; }
                }
                #pragma unroll
                for (int off = 32; off > 0; off >>= 1)
                    cls_lane += __shfl_down(cls_lane, off, 64);
                if (lane == 0) {
                    atomicAdd(&sh[lvl], lbox_u);
                    atomicAdd(&sh[3 + lvl], cls_lane);
                    atomicAdd(&sh[6 + lvl], (float)ne);
                    atomicAdd(&sh[9 + lvl], -lobj_u);
                }
            }
        }
    }
    __syncthreads();
    if (tid < 12) g_part[blockIdx.x * 12 + tid] = sh[tid];

    // ===== last-block-done fused reduction =====
    if (tid == 0) {
        __threadfence();                       // release g_part partials
        int old = atomicAdd(&g_done, 1);
        lastFlag = (old == nblk - 1);
    }
    __syncthreads();
    if (!lastFlag) return;
    __threadfence();                           // acquire all g_part partials

    __shared__ float red[12][TPB];
    float loc[12];
    #pragma unroll
    for (int c = 0; c < 12; c++) loc[c] = 0.0f;
    const float4* gp4 = (const float4*)g_part;  // 12 floats = 3 float4 / block
    for (int b = tid; b < nblk; b += TPB) {
        float4 a = gp4[b * 3];
        float4 bb = gp4[b * 3 + 1];
        float4 cc = gp4[b * 3 + 2];
        loc[0] += a.x;  loc[1] += a.y;  loc[2] += a.z;  loc[3] += a.w;
        loc[4] += bb.x; loc[5] += bb.y; loc[6] += bb.z; loc[7] += bb.w;
        loc[8] += cc.x; loc[9] += cc.y; loc[10] += cc.z; loc[11] += cc.w;
    }
    #pragma unroll
    for (int c = 0; c < 12; c++) red[c][tid] = loc[c];
    __syncthreads();
    for (int st = TPB / 2; st > 0; st >>= 1) {
        if (tid < st) {
            #pragma unroll
            for (int c = 0; c < 12; c++) red[c][tid] += red[c][tid + st];
        }
        __syncthreads();
    }
    if (tid == 0) {
        const float BAL[3] = {4.0f, 1.0f, 0.4f};
        const float NCF[3] = {(float)N0, (float)N1, (float)N2};
        float lbox = 0.0f, lcls = 0.0f, lobj = 0.0f;
        for (int l = 0; l < 3; l++) {
            float n = red[6 + l][0];
            if (n > 0.5f) {
                lbox += red[l][0] / n;
                lcls += red[3 + l][0] / (n * (float)NCLS);
            }
            lobj += red[9 + l][0] / NCF[l] * BAL[l];
        }
        lbox *= 7.5f;  // BOX_W
        lcls *= 0.5f;  // CLS_W
        float loss = (lbox + lobj + lcls) * (float)BATCH;
        out[0] = loss;
        out[1] = lbox;
        out[2] = lobj;
        out[3] = lcls;
        g_done = 0;    // self-reset for the next replay
    }
}

extern "C" void kernel_launch(void* const* d_in, const int* in_sizes, int n_in,
                              void* d_out, int out_size, void* d_ws, size_t ws_size,
                              hipStream_t stream) {
    const float* p0 = (const float*)d_in[0];
    const float* p1 = (const float*)d_in[1];
    const float* p2 = (const float*)d_in[2];
    const float* tg = (const float*)d_in[3];
    int nt = in_sizes[3] / 6;
    float* out = (float*)d_out;

    int nWaveTasks = 3 * nt;                       // one wave per (level,target)
    int tgtBlocks = (nWaveTasks + WPB - 1) / WPB;  // 4 waves per block
    if (tgtBlocks > NBMAX - STREAM_BLOCKS) tgtBlocks = NBMAX - STREAM_BLOCKS;
    int nblk = tgtBlocks + STREAM_BLOCKS;

    main_kernel<<<nblk, TPB, 0, stream>>>(p0, p1, p2, tg, nt, tgtBlocks, nblk,
                                          out);
}

// Round 7
// 117.178 us; speedup vs baseline: 1.7496x; 1.7496x over previous
//
#include <hip/hip_runtime.h>

#define NCLS 80
#define BATCH 32
#define N0 (BATCH * 80 * 80)   // 204800 cells, level 0
#define N1 (BATCH * 40 * 40)   // 51200
#define N2 (BATCH * 20 * 20)   // 12800
#define TPB 256
#define WPB (TPB / 64)         // waves per block
#define OBJ_BLOCKS ((N0 + N1 + N2) / TPB)  // 1050 (all exact multiples)
#define OBJ_B0 (N0 / TPB)      // 800 blocks -> level 0
#define OBJ_B01 ((N0 + N1) / TPB)  // 1000 -> level 1 boundary
#define NBMAX 1500             // OBJ_BLOCKS + up to 450 target blocks

// Per-block partials: [0..2]=lbox_s, [3..5]=lcls_s, [6..8]=cnt, [9..11]=lobj_s
// Written unconditionally by every block every call -> no zero-init needed.
__device__ float g_part[NBMAX * 12];

__device__ __forceinline__ float sigmoid_f(float x) {
    return 1.0f / (1.0f + expf(-x));
}

__device__ __forceinline__ float softplus_f(float x) {
    // stable: max(x,0) + log1p(exp(-|x|))
    return fmaxf(x, 0.0f) + log1pf(expf(-fabsf(x)));
}

__device__ __forceinline__ float ciou_f(float px, float py, float pw, float ph,
                                        float tx, float ty, float tw, float th) {
    const float eps = 1e-7f;
    float b1x1 = px - pw * 0.5f, b1x2 = px + pw * 0.5f;
    float b1y1 = py - ph * 0.5f, b1y2 = py + ph * 0.5f;
    float b2x1 = tx - tw * 0.5f, b2x2 = tx + tw * 0.5f;
    float b2y1 = ty - th * 0.5f, b2y2 = ty + th * 0.5f;
    float iw = fmaxf(fminf(b1x2, b2x2) - fmaxf(b1x1, b2x1), 0.0f);
    float ih = fmaxf(fminf(b1y2, b2y2) - fmaxf(b1y1, b2y1), 0.0f);
    float inter = iw * ih;
    float uni = pw * ph + tw * th - inter + eps;
    float iou = inter / uni;
    float cw = fmaxf(b1x2, b2x2) - fminf(b1x1, b2x1);
    float ch = fmaxf(b1y2, b2y2) - fminf(b1y1, b2y1);
    float c2 = cw * cw + ch * ch + eps;
    float dx = b2x1 + b2x2 - b1x1 - b1x2;
    float dy = b2y1 + b2y2 - b1y1 - b1y2;
    float rho2 = (dx * dx + dy * dy) * 0.25f;
    float dat = atanf(tw / th) - atanf(pw / ph);
    const float k = 0.40528473456935108577551785f; // 4/pi^2
    float v = k * dat * dat;
    float alpha = v / (v - iou + (1.0f + eps));
    return iou - (rho2 / c2 + v * alpha);
}

__global__ __launch_bounds__(TPB) void main_kernel(
        const float* __restrict__ p0,
        const float* __restrict__ p1,
        const float* __restrict__ p2,
        const float* __restrict__ tg, int nt, int tgtBlocks) {
    __shared__ float sh[12];
    int tid = threadIdx.x;
    if (tid < 12) sh[tid] = 0.0f;
    __syncthreads();

    if ((int)blockIdx.x >= tgtBlocks) {
        // ===== objectness gather path: one THREAD per cell =====
        // Touches exactly one 64B line per cell (17.2 MB total) with
        // 268,800 fully independent loads -> latency-bound but massively
        // parallel (~4200 wave-loads across 256 CUs). Beats streaming the
        // full 91.4 MB tensor (round-5/6 evidence: stream ~35-40 us).
        // Block-uniform level: region boundaries are multiples of TPB.
        int ob = blockIdx.x - tgtBlocks;       // 0..1049
        int lvl, cb;
        const float* p;
        if (ob < OBJ_B0)       { lvl = 0; cb = ob;            p = p0; }
        else if (ob < OBJ_B01) { lvl = 1; cb = ob - OBJ_B0;   p = p1; }
        else                   { lvl = 2; cb = ob - OBJ_B01;  p = p2; }
        int cell = cb * TPB + tid;
        float xo = p[(size_t)cell * (NCLS + 5) + 4];
        float v = softplus_f(xo);
        #pragma unroll
        for (int off = 32; off > 0; off >>= 1)
            v += __shfl_down(v, off, 64);
        if ((tid & 63) == 0) atomicAdd(&sh[9 + lvl], v);
    } else {
        // ===== target path: ONE WAVE per (level, target) =====
        // 85-float pred row read as two coalesced wave loads (pr[lane],
        // pr[64+lane] for lane<21); class softplus lane-parallel; box/obj
        // channels broadcast via shfl; CIoU computed uniformly on all lanes.
        int lane = tid & 63;
        int wtask = blockIdx.x * WPB + (tid >> 6);
        if (wtask < 3 * nt) {
            int lvl = wtask / nt;
            int t = wtask - lvl * nt;

            int W = (lvl == 0) ? 80 : ((lvl == 1) ? 40 : 20);
            float s = (lvl == 0) ? 8.0f : ((lvl == 1) ? 16.0f : 32.0f);
            const float* p = (lvl == 0) ? p0 : ((lvl == 1) ? p1 : p2);

            const float* row = tg + t * 6;
            float bf = row[0], cf = row[1];
            float x = row[2], y = row[3], w = row[4], h = row[5];

            float Wf = (float)W;
            float gw = w * Wf, gh = h * Wf;   // gain (H == W per level)
            float rw = gw / s, rh = gh / s;
            float m = fmaxf(fmaxf(rw, 1.0f / rw), fmaxf(rh, 1.0f / rh));
            if (m < 4.0f) {                   // keep filter (wave-uniform)
                float gx = x * Wf, gy = y * Wf;
                int b = (int)bf;
                int c = (int)cf;

                // offset candidates; jj/ll and kk/mm mutually exclusive -> ne<=3
                float ox[3], oy[3];
                int ne = 0;
                ox[ne] = 0.0f; oy[ne] = 0.0f; ne++;
                bool jj = (fmodf(gx, 1.0f) < 0.5f) && (gx > 1.0f);
                bool kk = (fmodf(gy, 1.0f) < 0.5f) && (gy > 1.0f);
                float gxi = Wf - gx, gyi = Wf - gy;
                bool ll = (fmodf(gxi, 1.0f) < 0.5f) && (gxi > 1.0f);
                bool mm = (fmodf(gyi, 1.0f) < 0.5f) && (gyi > 1.0f);
                if (jj) { ox[ne] = 0.5f;  oy[ne] = 0.0f;  ne++; }
                if (ll) { ox[ne] = -0.5f; oy[ne] = 0.0f;  ne++; }
                if (kk) { ox[ne] = 0.0f;  oy[ne] = 0.5f;  ne++; }
                if (mm) { ox[ne] = 0.0f;  oy[ne] = -0.5f; ne++; }

                float cls_lane = 0.0f;        // distributed across lanes
                float lbox_u = 0.0f, lobj_u = 0.0f;  // wave-uniform
                int hot = 5 + c;              // one-hot class channel
                for (int e = 0; e < ne; e++) {
                    int gi = (int)(gx - ox[e]);  // operands > 0: trunc == floor
                    int gj = (int)(gy - oy[e]);
                    gi = min(max(gi, 0), W - 1);
                    gj = min(max(gj, 0), W - 1);
                    int cell = (b * W + gj) * W + gi;  // a == 0
                    const float* pr = p + (size_t)cell * (NCLS + 5);

                    float v1 = pr[lane];                              // 0..63
                    float v2 = (lane < 21) ? pr[64 + lane] : 0.0f;    // 64..84

                    float c0 = __shfl(v1, 0, 64);
                    float c1 = __shfl(v1, 1, 64);
                    float c2 = __shfl(v1, 2, 64);
                    float c3 = __shfl(v1, 3, 64);
                    float c4 = __shfl(v1, 4, 64);

                    float px = sigmoid_f(c0) * 2.0f - 0.5f;
                    float py = sigmoid_f(c1) * 2.0f - 0.5f;
                    float sw = sigmoid_f(c2) * 2.0f;
                    float shh = sigmoid_f(c3) * 2.0f;
                    float pw = sw * sw * s;
                    float ph = shh * shh * s;

                    float tbx = gx - (float)gi;
                    float tby = gy - (float)gj;

                    float iou = ciou_f(px, py, pw, ph, tbx, tby, gw, gh);
                    lbox_u += 1.0f - iou;
                    lobj_u += c4 * fmaxf(iou, 0.0f);  // x4 * tobj scatter term

                    // class BCE: sum softplus over channels 5..84, minus the
                    // logit at the one-hot channel
                    float s1 = (lane >= 5) ? softplus_f(v1) : 0.0f;
                    float s2 = (lane < 21) ? softplus_f(v2) : 0.0f;
                    cls_lane += s1 + s2;
                    if (hot < 64) { if (lane == hot)      cls_lane -= v1; }
                    else          { if (lane == hot - 64) cls_lane -= v2; }
                }
                #pragma unroll
                for (int off = 32; off > 0; off >>= 1)
                    cls_lane += __shfl_down(cls_lane, off, 64);
                if (lane == 0) {
                    atomicAdd(&sh[lvl], lbox_u);
                    atomicAdd(&sh[3 + lvl], cls_lane);
                    atomicAdd(&sh[6 + lvl], (float)ne);
                    atomicAdd(&sh[9 + lvl], -lobj_u);
                }
            }
        }
    }
    __syncthreads();
    if (tid < 12) g_part[blockIdx.x * 12 + tid] = sh[tid];
}

__global__ __launch_bounds__(TPB) void reduce_kernel(float* __restrict__ out,
                                                     int nblk) {
    __shared__ float red[12][TPB];
    int tid = threadIdx.x;
    float loc[12];
    #pragma unroll
    for (int c = 0; c < 12; c++) loc[c] = 0.0f;
    const float4* gp4 = (const float4*)g_part;  // 12 floats = 3 float4 / block
    for (int b = tid; b < nblk; b += TPB) {
        float4 a = gp4[b * 3];
        float4 bb = gp4[b * 3 + 1];
        float4 cc = gp4[b * 3 + 2];
        loc[0] += a.x;  loc[1] += a.y;  loc[2] += a.z;  loc[3] += a.w;
        loc[4] += bb.x; loc[5] += bb.y; loc[6] += bb.z; loc[7] += bb.w;
        loc[8] += cc.x; loc[9] += cc.y; loc[10] += cc.z; loc[11] += cc.w;
    }
    #pragma unroll
    for (int c = 0; c < 12; c++) red[c][tid] = loc[c];
    __syncthreads();
    for (int st = TPB / 2; st > 0; st >>= 1) {
        if (tid < st) {
            #pragma unroll
            for (int c = 0; c < 12; c++) red[c][tid] += red[c][tid + st];
        }
        __syncthreads();
    }
    if (tid == 0) {
        const float BAL[3] = {4.0f, 1.0f, 0.4f};
        const float NCF[3] = {(float)N0, (float)N1, (float)N2};
        float lbox = 0.0f, lcls = 0.0f, lobj = 0.0f;
        for (int l = 0; l < 3; l++) {
            float n = red[6 + l][0];
            if (n > 0.5f) {
                lbox += red[l][0] / n;
                lcls += red[3 + l][0] / (n * (float)NCLS);
            }
            lobj += red[9 + l][0] / NCF[l] * BAL[l];
        }
        lbox *= 7.5f;  // BOX_W
        lcls *= 0.5f;  // CLS_W
        float loss = (lbox + lobj + lcls) * (float)BATCH;
        out[0] = loss;
        out[1] = lbox;
        out[2] = lobj;
        out[3] = lcls;
    }
}

extern "C" void kernel_launch(void* const* d_in, const int* in_sizes, int n_in,
                              void* d_out, int out_size, void* d_ws, size_t ws_size,
                              hipStream_t stream) {
    const float* p0 = (const float*)d_in[0];
    const float* p1 = (const float*)d_in[1];
    const float* p2 = (const float*)d_in[2];
    const float* tg = (const float*)d_in[3];
    int nt = in_sizes[3] / 6;
    float* out = (float*)d_out;

    int nWaveTasks = 3 * nt;                       // one wave per (level,target)
    int tgtBlocks = (nWaveTasks + WPB - 1) / WPB;  // 4 waves per block
    if (tgtBlocks > NBMAX - OBJ_BLOCKS) tgtBlocks = NBMAX - OBJ_BLOCKS;
    int nblk = tgtBlocks + OBJ_BLOCKS;

    main_kernel<<<nblk, TPB, 0, stream>>>(p0, p1, p2, tg, nt, tgtBlocks);
    reduce_kernel<<<1, TPB, 0, stream>>>(out, nblk);
}